// Round 1
// baseline (495.855 us; speedup 1.0000x reference)
//
#include <hip/hip_runtime.h>

typedef __attribute__((ext_vector_type(8))) short bf8_t;   // 8 bf16 = 4 VGPRs
typedef __attribute__((ext_vector_type(4))) float f4_t;

#define MFMA16(a, b, c) __builtin_amdgcn_mfma_f32_16x16x32_bf16((a), (b), (c), 0, 0, 0)

// ws layout (bf16 element offsets)
#define OFF_FC1 0          // 64*128
#define OFF_FC2 8192       // 64*192
#define OFF_FC3 20480      // 32*64
#define OFF_AB1 22528      // 256*256
#define OFF_AB2 88064      // 256*256
#define W_TOTAL 153600

// LDS row stride in bf16 elements. cols [0:128) = x_bf16 then z_hx/z2,
// [128:384) = tanh(x)||tanh(m) then h1.  384+8 pad -> row-to-row bank shift 4 (2-way, free).
#define ST 392

__device__ __forceinline__ unsigned short f2bf(float f) {
    unsigned int u = __builtin_bit_cast(unsigned int, f);
    u += 0x7FFFu + ((u >> 16) & 1u);               // round-to-nearest-even
    return (unsigned short)(u >> 16);
}

__device__ __forceinline__ float fast_tanh(float x) {
    // tanh(x) = 1 - 2/(exp2(2*log2(e)*x)+1); correct limits at +-inf
    float e = __builtin_amdgcn_exp2f(x * 2.885390081777927f);
    return 1.0f - 2.0f * __builtin_amdgcn_rcpf(e + 1.0f);
}

__global__ void convert_weights_kernel(const float* __restrict__ fc1w, const float* __restrict__ fc2w,
                                       const float* __restrict__ fc3w, const float* __restrict__ ab1w,
                                       const float* __restrict__ ab2w, unsigned short* __restrict__ wc) {
    int i = blockIdx.x * 256 + threadIdx.x;
    if (i >= W_TOTAL) return;
    float v;
    if (i < OFF_FC2)      v = fc1w[i];
    else if (i < OFF_FC3) v = fc2w[i - OFF_FC2];
    else if (i < OFF_AB1) v = fc3w[i - OFF_FC3];
    else if (i < OFF_AB2) v = ab1w[i - OFF_AB1];
    else                  v = ab2w[i - OFF_AB2];
    wc[i] = f2bf(v);
}

__global__ __launch_bounds__(256, 3)
void actor_fused_kernel(const float* __restrict__ x, const float* __restrict__ m,
                        const float* __restrict__ fc1_b, const float* __restrict__ fc2_b,
                        const float* __restrict__ fc3_b,
                        const float* __restrict__ ab_b1, const float* __restrict__ ab_b2,
                        const float* __restrict__ ab_w3, const float* __restrict__ ab_b3,
                        const unsigned short* __restrict__ wc,
                        float* __restrict__ out, int Brows)
{
    __shared__ __align__(16) unsigned short smem[64 * ST];
    __shared__ float pw[4][64];

    const int t    = threadIdx.x;
    const int wave = t >> 6;
    const int lane = t & 63;
    const int l15  = lane & 15;
    const int quad = lane >> 4;
    const int r0   = blockIdx.x * 64;          // first batch row of this block
    const int mrow = wave * 16;                // this wave's row offset (message branch)

    // ---------------- stage: x -> bf16 + tanh(x); m -> tanh(m) ----------------
    {
        const float* xp = x + (size_t)r0 * 128;
        const float* mp = m + (size_t)r0 * 128;
        #pragma unroll
        for (int i = 0; i < 8; i++) {
            int idx = t * 4 + i * 1024;        // coalesced float4 over [0,8192)
            int row = idx >> 7, col = idx & 127;
            float4 v = *(const float4*)(xp + idx);
            ushort4 raw;
            raw.x = f2bf(v.x); raw.y = f2bf(v.y); raw.z = f2bf(v.z); raw.w = f2bf(v.w);
            *(ushort4*)&smem[row * ST + col] = raw;
            ushort4 tx;
            tx.x = f2bf(fast_tanh(v.x)); tx.y = f2bf(fast_tanh(v.y));
            tx.z = f2bf(fast_tanh(v.z)); tx.w = f2bf(fast_tanh(v.w));
            *(ushort4*)&smem[row * ST + 128 + col] = tx;
            float4 w = *(const float4*)(mp + idx);
            ushort4 tm;
            tm.x = f2bf(fast_tanh(w.x)); tm.y = f2bf(fast_tanh(w.y));
            tm.z = f2bf(fast_tanh(w.z)); tm.w = f2bf(fast_tanh(w.w));
            *(ushort4*)&smem[row * ST + 256 + col] = tm;
        }
    }
    __syncthreads();

    // ---------------- fc1: hx = x @ fc1_w^T + b   (per-wave, own 16 rows) ----------------
    f4_t hx[4] = {f4_t{0,0,0,0}, f4_t{0,0,0,0}, f4_t{0,0,0,0}, f4_t{0,0,0,0}};
    #pragma unroll
    for (int k = 0; k < 4; k++) {
        bf8_t a = *(const bf8_t*)&smem[(mrow + l15) * ST + k * 32 + quad * 8];
        #pragma unroll
        for (int nt = 0; nt < 4; nt++) {
            bf8_t b = *(const bf8_t*)(wc + OFF_FC1 + (nt * 16 + l15) * 128 + k * 32 + quad * 8);
            hx[nt] = MFMA16(a, b, hx[nt]);
        }
    }
    {
        float bia[4], ss[4] = {0, 0, 0, 0};
        #pragma unroll
        for (int nt = 0; nt < 4; nt++) bia[nt] = fc1_b[nt * 16 + l15];
        #pragma unroll
        for (int nt = 0; nt < 4; nt++)
            #pragma unroll
            for (int r = 0; r < 4; r++) { hx[nt][r] += bia[nt]; ss[r] += hx[nt][r] * hx[nt][r]; }
        #pragma unroll
        for (int off = 1; off < 16; off <<= 1)
            #pragma unroll
            for (int r = 0; r < 4; r++) ss[r] += __shfl_xor(ss[r], off, 64);
        float inv[4];
        #pragma unroll
        for (int r = 0; r < 4; r++) inv[r] = rsqrtf(fmaxf(ss[r], 1e-24f));
        // z_hx = tanh(l2norm(hx)) -> cols [0:64)
        #pragma unroll
        for (int nt = 0; nt < 4; nt++)
            #pragma unroll
            for (int r = 0; r < 4; r++)
                smem[(mrow + quad * 4 + r) * ST + nt * 16 + l15] = f2bf(fast_tanh(hx[nt][r] * inv[r]));
    }
    __syncthreads();

    // ---------------- fc2: z2 = tanh(concat(z_hx, tanh(m)) @ fc2_w^T + b)  K=192 ----------------
    f4_t z2[4] = {f4_t{0,0,0,0}, f4_t{0,0,0,0}, f4_t{0,0,0,0}, f4_t{0,0,0,0}};
    #pragma unroll
    for (int k = 0; k < 6; k++) {
        int acol = (k < 2) ? (k * 32 + quad * 8) : (192 + k * 32 + quad * 8); // z_hx | tanh(m)
        bf8_t a = *(const bf8_t*)&smem[(mrow + l15) * ST + acol];
        #pragma unroll
        for (int nt = 0; nt < 4; nt++) {
            bf8_t b = *(const bf8_t*)(wc + OFF_FC2 + (nt * 16 + l15) * 192 + k * 32 + quad * 8);
            z2[nt] = MFMA16(a, b, z2[nt]);
        }
    }
    {
        float bia[4];
        #pragma unroll
        for (int nt = 0; nt < 4; nt++) bia[nt] = fc2_b[nt * 16 + l15];
        #pragma unroll
        for (int nt = 0; nt < 4; nt++)
            #pragma unroll
            for (int r = 0; r < 4; r++)
                smem[(mrow + quad * 4 + r) * ST + 64 + nt * 16 + l15] = f2bf(fast_tanh(z2[nt][r] + bia[nt]));
    }
    __syncthreads();

    // ---------------- fc3: msg = l2norm(z2 @ fc3_w^T + b)  K=64, N=32 ----------------
    {
        f4_t mg[2] = {f4_t{0,0,0,0}, f4_t{0,0,0,0}};
        #pragma unroll
        for (int k = 0; k < 2; k++) {
            bf8_t a = *(const bf8_t*)&smem[(mrow + l15) * ST + 64 + k * 32 + quad * 8];
            #pragma unroll
            for (int nt = 0; nt < 2; nt++) {
                bf8_t b = *(const bf8_t*)(wc + OFF_FC3 + (nt * 16 + l15) * 64 + k * 32 + quad * 8);
                mg[nt] = MFMA16(a, b, mg[nt]);
            }
        }
        float bia[2], ss[4] = {0, 0, 0, 0};
        #pragma unroll
        for (int nt = 0; nt < 2; nt++) bia[nt] = fc3_b[nt * 16 + l15];
        #pragma unroll
        for (int nt = 0; nt < 2; nt++)
            #pragma unroll
            for (int r = 0; r < 4; r++) { mg[nt][r] += bia[nt]; ss[r] += mg[nt][r] * mg[nt][r]; }
        #pragma unroll
        for (int off = 1; off < 16; off <<= 1)
            #pragma unroll
            for (int r = 0; r < 4; r++) ss[r] += __shfl_xor(ss[r], off, 64);
        float inv[4];
        #pragma unroll
        for (int r = 0; r < 4; r++) inv[r] = rsqrtf(fmaxf(ss[r], 1e-24f));
        #pragma unroll
        for (int nt = 0; nt < 2; nt++)
            #pragma unroll
            for (int r = 0; r < 4; r++)
                out[(size_t)(r0 + mrow + quad * 4 + r) * 32 + nt * 16 + l15] = mg[nt][r] * inv[r];
    }

    // ---------------- ab1: h1 = relu(xm @ w1^T + b1)  block-coop: wave owns 64-col N-chunk ----------------
    const int n0 = wave * 64;
    f4_t acc[4][4];
    #pragma unroll
    for (int ms = 0; ms < 4; ms++)
        #pragma unroll
        for (int nt = 0; nt < 4; nt++) acc[ms][nt] = f4_t{0, 0, 0, 0};
    #pragma unroll
    for (int k = 0; k < 8; k++) {
        bf8_t a[4];
        #pragma unroll
        for (int ms = 0; ms < 4; ms++)
            a[ms] = *(const bf8_t*)&smem[(ms * 16 + l15) * ST + 128 + k * 32 + quad * 8];
        #pragma unroll
        for (int nt = 0; nt < 4; nt++) {
            bf8_t b = *(const bf8_t*)(wc + OFF_AB1 + (n0 + nt * 16 + l15) * 256 + k * 32 + quad * 8);
            #pragma unroll
            for (int ms = 0; ms < 4; ms++) acc[ms][nt] = MFMA16(a[ms], b, acc[ms][nt]);
        }
    }
    {
        float bia[4];
        #pragma unroll
        for (int nt = 0; nt < 4; nt++) bia[nt] = ab_b1[n0 + nt * 16 + l15];
        __syncthreads();   // all waves done reading tanh(x)||tanh(m) before h1 overwrites it
        #pragma unroll
        for (int ms = 0; ms < 4; ms++)
            #pragma unroll
            for (int nt = 0; nt < 4; nt++)
                #pragma unroll
                for (int r = 0; r < 4; r++)
                    smem[(ms * 16 + quad * 4 + r) * ST + 128 + n0 + nt * 16 + l15] =
                        f2bf(fmaxf(acc[ms][nt][r] + bia[nt], 0.0f));
    }
    __syncthreads();

    // ---------------- ab2: h2 = relu(h1 @ w2^T + b2), fused with ab3 dot ----------------
    f4_t acc2[4][4];
    #pragma unroll
    for (int ms = 0; ms < 4; ms++)
        #pragma unroll
        for (int nt = 0; nt < 4; nt++) acc2[ms][nt] = f4_t{0, 0, 0, 0};
    #pragma unroll
    for (int k = 0; k < 8; k++) {
        bf8_t a[4];
        #pragma unroll
        for (int ms = 0; ms < 4; ms++)
            a[ms] = *(const bf8_t*)&smem[(ms * 16 + l15) * ST + 128 + k * 32 + quad * 8];
        #pragma unroll
        for (int nt = 0; nt < 4; nt++) {
            bf8_t b = *(const bf8_t*)(wc + OFF_AB2 + (n0 + nt * 16 + l15) * 256 + k * 32 + quad * 8);
            #pragma unroll
            for (int ms = 0; ms < 4; ms++) acc2[ms][nt] = MFMA16(a[ms], b, acc2[ms][nt]);
        }
    }
    {
        float bia[4], w3v[4];
        #pragma unroll
        for (int nt = 0; nt < 4; nt++) { bia[nt] = ab_b2[n0 + nt * 16 + l15]; w3v[nt] = ab_w3[n0 + nt * 16 + l15]; }
        float p[4][4];
        #pragma unroll
        for (int ms = 0; ms < 4; ms++)
            #pragma unroll
            for (int r = 0; r < 4; r++) {
                float s = 0.0f;
                #pragma unroll
                for (int nt = 0; nt < 4; nt++) s += fmaxf(acc2[ms][nt][r] + bia[nt], 0.0f) * w3v[nt];
                p[ms][r] = s;
            }
        #pragma unroll
        for (int off = 1; off < 16; off <<= 1)
            #pragma unroll
            for (int ms = 0; ms < 4; ms++)
                #pragma unroll
                for (int r = 0; r < 4; r++) p[ms][r] += __shfl_xor(p[ms][r], off, 64);
        if (l15 == 0) {
            #pragma unroll
            for (int ms = 0; ms < 4; ms++)
                #pragma unroll
                for (int r = 0; r < 4; r++) pw[wave][ms * 16 + quad * 4 + r] = p[ms][r];
        }
    }
    __syncthreads();
    if (t < 64) {
        float a = pw[0][t] + pw[1][t] + pw[2][t] + pw[3][t] + ab_b3[0];
        out[(size_t)Brows * 32 + r0 + t] = fast_tanh(a);   // MAX_ACTION = 1
    }
}

extern "C" void kernel_launch(void* const* d_in, const int* in_sizes, int n_in,
                              void* d_out, int out_size, void* d_ws, size_t ws_size,
                              hipStream_t stream) {
    const float* x     = (const float*)d_in[0];
    const float* m     = (const float*)d_in[1];
    const float* fc1_w = (const float*)d_in[2];
    const float* fc1_b = (const float*)d_in[3];
    const float* fc2_w = (const float*)d_in[4];
    const float* fc2_b = (const float*)d_in[5];
    const float* fc3_w = (const float*)d_in[6];
    const float* fc3_b = (const float*)d_in[7];
    const float* ab_w1 = (const float*)d_in[8];
    const float* ab_b1 = (const float*)d_in[9];
    const float* ab_w2 = (const float*)d_in[10];
    const float* ab_b2 = (const float*)d_in[11];
    const float* ab_w3 = (const float*)d_in[12];
    const float* ab_b3 = (const float*)d_in[13];
    float* out = (float*)d_out;
    unsigned short* wc = (unsigned short*)d_ws;
    int Brows = in_sizes[0] / 128;   // 262144

    convert_weights_kernel<<<(W_TOTAL + 255) / 256, 256, 0, stream>>>(fc1_w, fc2_w, fc3_w, ab_w1, ab_w2, wc);
    actor_fused_kernel<<<Brows / 64, 256, 0, stream>>>(x, m, fc1_b, fc2_b, fc3_b,
                                                       ab_b1, ab_b2, ab_w3, ab_b3, wc, out, Brows);
}